// Round 1
// baseline (860.096 us; speedup 1.0000x reference)
//
#include <hip/hip_runtime.h>

#define BQ 64        // batch (query rows)
#define MB 256       // bank entries (sim columns)
#define DK 524288    // feature dim (K)
#define SS 2048      // style dim
#define CH 32        // K-chunk depth per staging iteration
#define TPB 256

// ---------------------------------------------------------------------------
// K1: fused partial matmul + column sum-of-squares.
//   sim_raw[b,m] = sum_d content[b*DK+d] * bank[d*MB+m]   (ct = raw reshape!)
//   cn[m]       = sum_d bank[d*MB+m]^2
// Grid-stride over K-chunks; each block accumulates its chunks in registers,
// then flushes one deterministic partial tile to ws (no atomics).
// LDS: cs tile stored transposed [d][b] so inner-loop reads are b128 +
// 8-lane broadcast (conflict-free); ct tile [d][m] likewise.
// ---------------------------------------------------------------------------
__global__ __launch_bounds__(TPB, 4) void k1_partial(
    const float* __restrict__ content, const float* __restrict__ bank,
    float* __restrict__ psim, float* __restrict__ pcn, int G)
{
    __shared__ float cs_t[CH * BQ];   // [d][b]  8 KB
    __shared__ float ct_t[CH * MB];   // [d][m] 32 KB
    const int tid = threadIdx.x;
    const int g   = blockIdx.x;
    const int tb  = tid & 7;          // b-tile: b = tb*8 + i
    const int tm  = tid >> 3;         // m-tile: m = tm*8 + j

    float acc[8][8];
    #pragma unroll
    for (int i = 0; i < 8; ++i)
        #pragma unroll
        for (int j = 0; j < 8; ++j) acc[i][j] = 0.f;
    // each thread's staged ct float4s always hit m = (tid&63)*4 .. +3
    float cn0 = 0.f, cn1 = 0.f, cn2 = 0.f, cn3 = 0.f;

    const int NC = DK / CH;           // 16384 chunks
    for (int c = g; c < NC; c += G) {
        const int d0 = c * CH;
        __syncthreads();              // previous iter's LDS reads done
        // ---- stage ct chunk (contiguous 8192 floats) + fused sumsq ----
        {
            const float4* src = (const float4*)(bank + (size_t)d0 * MB);
            float4* dst = (float4*)ct_t;
            #pragma unroll
            for (int k = 0; k < 8; ++k) {
                float4 v = src[tid + k * 256];
                dst[tid + k * 256] = v;
                cn0 = fmaf(v.x, v.x, cn0);
                cn1 = fmaf(v.y, v.y, cn1);
                cn2 = fmaf(v.z, v.z, cn2);
                cn3 = fmaf(v.w, v.w, cn3);
            }
        }
        // ---- stage cs chunk transposed: cs_t[d][b] ----
        #pragma unroll
        for (int p = 0; p < 2; ++p) {
            int q  = tid + p * 256;        // 0..511 : 64 rows x 8 float4
            int b  = q >> 3, c4 = q & 7;
            float4 v = *(const float4*)(content + (size_t)b * DK + d0 + c4 * 4);
            int dd = c4 * 4;
            cs_t[(dd + 0) * BQ + b] = v.x;
            cs_t[(dd + 1) * BQ + b] = v.y;
            cs_t[(dd + 2) * BQ + b] = v.z;
            cs_t[(dd + 3) * BQ + b] = v.w;
        }
        __syncthreads();
        // ---- 8x8 register-tile outer product over the chunk ----
        #pragma unroll 2
        for (int d = 0; d < CH; ++d) {
            float4 a0 = *(const float4*)&cs_t[d * BQ + tb * 8];
            float4 a1 = *(const float4*)&cs_t[d * BQ + tb * 8 + 4];
            float4 b0 = *(const float4*)&ct_t[d * MB + tm * 8];
            float4 b1 = *(const float4*)&ct_t[d * MB + tm * 8 + 4];
            float av[8] = {a0.x, a0.y, a0.z, a0.w, a1.x, a1.y, a1.z, a1.w};
            float bv[8] = {b0.x, b0.y, b0.z, b0.w, b1.x, b1.y, b1.z, b1.w};
            #pragma unroll
            for (int i = 0; i < 8; ++i)
                #pragma unroll
                for (int j = 0; j < 8; ++j)
                    acc[i][j] = fmaf(av[i], bv[j], acc[i][j]);
        }
    }

    // ---- flush sim partial tile ----
    {
        float* outp = psim + (size_t)g * (BQ * MB);
        #pragma unroll
        for (int i = 0; i < 8; ++i) {
            int b = tb * 8 + i;
            *(float4*)&outp[b * MB + tm * 8] =
                make_float4(acc[i][0], acc[i][1], acc[i][2], acc[i][3]);
            *(float4*)&outp[b * MB + tm * 8 + 4] =
                make_float4(acc[i][4], acc[i][5], acc[i][6], acc[i][7]);
        }
    }
    // ---- flush colnorm partial: LDS transpose-reduce (reuse ct_t) ----
    __syncthreads();
    *(float4*)&ct_t[tid * 4] = make_float4(cn0, cn1, cn2, cn3);
    __syncthreads();
    {
        int m = tid;                       // 0..255
        int tsrc = m >> 2, comp = m & 3;   // contributors: tsrc + 64*w
        float v = ct_t[(tsrc      ) * 4 + comp]
                + ct_t[(tsrc +  64) * 4 + comp]
                + ct_t[(tsrc + 128) * 4 + comp]
                + ct_t[(tsrc + 192) * 4 + comp];
        pcn[(size_t)g * MB + m] = v;
    }
}

// ---------------------------------------------------------------------------
// K2: reduce G partials -> 8 partials (deterministic, no atomics).
// 16640 outputs (16384 sim + 256 cn) x 8 g-stripes; 520 blocks of 256.
// ---------------------------------------------------------------------------
__global__ void k2_reduce(const float* __restrict__ psim,
                          const float* __restrict__ pcn,
                          float* __restrict__ stage2, int G)
{
    const int r  = blockIdx.x % 65;
    const int gs = blockIdx.x / 65;
    const int o  = r * 256 + threadIdx.x;   // 0..16639
    float s = 0.f;
    if (o < BQ * MB) {
        for (int g = gs; g < G; g += 8) s += psim[(size_t)g * (BQ * MB) + o];
    } else {
        int m = o - BQ * MB;
        for (int g = gs; g < G; g += 8) s += pcn[(size_t)g * MB + m];
    }
    stage2[(size_t)gs * 16640 + o] = s;
}

// ---------------------------------------------------------------------------
// K3: per-row argmax (numpy first-index tie-break) + style-row gather.
// Query-side norm is a positive per-row scale -> skipped (argmax-invariant).
// ---------------------------------------------------------------------------
__global__ void k3_argmax_gather(const float* __restrict__ stage2,
                                 const float* __restrict__ bank_style,
                                 float* __restrict__ out)
{
    const int b = blockIdx.x;
    const int tid = threadIdx.x;          // == m
    float s = 0.f, c = 0.f;
    #pragma unroll
    for (int gs = 0; gs < 8; ++gs) {
        s += stage2[(size_t)gs * 16640 + b * MB + tid];
        c += stage2[(size_t)gs * 16640 + BQ * MB + tid];
    }
    float score = s / fmaxf(sqrtf(c), 1e-12f);

    float best = score; int bidx = tid;
    #pragma unroll
    for (int off = 32; off >= 1; off >>= 1) {   // wave64 reduce
        float os = __shfl_down(best, off);
        int   oi = __shfl_down(bidx, off);
        if (os > best || (os == best && oi < bidx)) { best = os; bidx = oi; }
    }
    __shared__ float wbest[4];
    __shared__ int   widx[4];
    __shared__ int   fidx;
    int wave = tid >> 6, lane = tid & 63;
    if (lane == 0) { wbest[wave] = best; widx[wave] = bidx; }
    __syncthreads();
    if (tid == 0) {
        float fb = wbest[0]; int fi = widx[0];
        #pragma unroll
        for (int w = 1; w < 4; ++w)
            if (wbest[w] > fb || (wbest[w] == fb && widx[w] < fi)) {
                fb = wbest[w]; fi = widx[w];
            }
        fidx = fi;
    }
    __syncthreads();
    const float4* srcr = (const float4*)(bank_style + (size_t)fidx * SS);
    float4*       dstr = (float4*)(out + (size_t)b * SS);
    for (int k = tid; k < SS / 4; k += TPB) dstr[k] = srcr[k];
}

// ---------------------------------------------------------------------------
extern "C" void kernel_launch(void* const* d_in, const int* in_sizes, int n_in,
                              void* d_out, int out_size, void* d_ws, size_t ws_size,
                              hipStream_t stream)
{
    const float* content      = (const float*)d_in[0];
    const float* bank_content = (const float*)d_in[1];
    const float* bank_style   = (const float*)d_in[2];
    float* out = (float*)d_out;

    // ws layout: psim[G][16384] | pcn[G][256] | stage2[8][16640]
    long long avail = (long long)(ws_size / 4) - 8LL * 16640;
    int G = (int)(avail / 16640);
    if (G > 1024) G = 1024;   // 4 blocks/CU on 256 CUs
    if (G < 1)    G = 1;

    float* psim   = (float*)d_ws;
    float* pcn    = psim + (size_t)G * (BQ * MB);
    float* stage2 = psim + (size_t)G * 16640;

    k1_partial<<<G, TPB, 0, stream>>>(content, bank_content, psim, pcn, G);
    k2_reduce<<<520, TPB, 0, stream>>>(psim, pcn, stage2, G);
    k3_argmax_gather<<<BQ, TPB, 0, stream>>>(stage2, bank_style, out);
}